// Round 1
// baseline (709.382 us; speedup 1.0000x reference)
//
#include <hip/hip_runtime.h>
#include <hip/hip_bf16.h>
#include <math.h>

typedef __bf16 bf16;
typedef __bf16 bf16x8 __attribute__((ext_vector_type(8)));
typedef float  f32x4  __attribute__((ext_vector_type(4)));

#define D_MODEL 768
#define MLP_DIM 3072

// ---------------- workspace layout (bytes, all 256-aligned by construction) ----
#define SZ_W1T   ((size_t)8*3072*768*2)        // 37748736  bf16 [E][N=3072][K=768]
#define SZ_W2T   ((size_t)8*768*3072*2)        // 37748736  bf16 [E][N=768][K=3072]
#define SZ_XED   ((size_t)8*8*256*768*2)       // 25165824  bf16 [E][G*C][768] det
#define SZ_XEC   ((size_t)8*8*32*768*2)        //  3145728  cls
#define SZ_HD    ((size_t)8*2048*3072*2)       // 100663296 bf16 [E][M][3072] det
#define SZ_HC    ((size_t)8*256*3072*2)        //  12582912 cls
#define SZ_RID   ((size_t)8192*8)              // int2 per det token
#define SZ_RGD   ((size_t)8192*8)              // float2 per det token
#define SZ_RIC   ((size_t)1024*8)
#define SZ_RGC   ((size_t)1024*8)
#define SZ_STD   ((size_t)8*8*256*4)           // slot_token det
#define SZ_STC   ((size_t)8*8*32*4)            // slot_token cls
#define SZ_SGD   ((size_t)8*8*256*4)           // slot_gate det
#define SZ_SGC   ((size_t)8*8*32*4)

#define OFF_W1T  ((size_t)0)
#define OFF_W2T  (OFF_W1T + SZ_W1T)
#define OFF_XED  (OFF_W2T + SZ_W2T)
#define OFF_XEC  (OFF_XED + SZ_XED)
#define OFF_HD   (OFF_XEC + SZ_XEC)
#define OFF_HC   (OFF_HD  + SZ_HD)
#define OFF_RID  (OFF_HC  + SZ_HC)
#define OFF_RGD  (OFF_RID + SZ_RID)
#define OFF_RIC  (OFF_RGD + SZ_RGD)
#define OFF_RGC  (OFF_RIC + SZ_RIC)
#define OFF_STD  (OFF_RGC + SZ_RGC)
#define OFF_STC  (OFF_STD + SZ_STD)            // STD+STC contiguous: one memset(0xFF)
#define OFF_SGD  (OFF_STC + SZ_STC)
#define OFF_SGC  (OFF_SGD + SZ_SGD)

// ---------------- helpers ------------------------------------------------------
__device__ __forceinline__ void lds_load16(const void* g, void* l) {
  __builtin_amdgcn_global_load_lds((__attribute__((address_space(1))) void*)g,
                                   (__attribute__((address_space(3))) void*)l,
                                   16, 0, 0);
}

__device__ __forceinline__ float gelu_tanh(float x) {
  float x3 = x * x * x;
  float t = tanhf(0.7978845608028654f * (x + 0.044715f * x3));
  return 0.5f * x * (1.f + t);
}

// ---------------- router: gates = softmax(x@wr), top-2 -------------------------
// one wave per token
__global__ void router_kernel(const float* __restrict__ x, const float* __restrict__ wr,
                              int ntok, int2* __restrict__ ridx, float2* __restrict__ rgate) {
  int wave = threadIdx.x >> 6;
  int lane = threadIdx.x & 63;
  int t = blockIdx.x * 4 + wave;
  if (t >= ntok) return;
  const float* xr = x + (size_t)t * D_MODEL;
  float acc[8];
#pragma unroll
  for (int e = 0; e < 8; ++e) acc[e] = 0.f;
  for (int d = lane; d < D_MODEL; d += 64) {
    float xv = xr[d];
    const float* w = wr + d * 8;
    float4 a = *(const float4*)w;
    float4 b = *(const float4*)(w + 4);
    acc[0] += xv * a.x; acc[1] += xv * a.y; acc[2] += xv * a.z; acc[3] += xv * a.w;
    acc[4] += xv * b.x; acc[5] += xv * b.y; acc[6] += xv * b.z; acc[7] += xv * b.w;
  }
#pragma unroll
  for (int off = 32; off > 0; off >>= 1) {
#pragma unroll
    for (int e = 0; e < 8; ++e) acc[e] += __shfl_xor(acc[e], off, 64);
  }
  float mx = acc[0];
#pragma unroll
  for (int e = 1; e < 8; ++e) mx = fmaxf(mx, acc[e]);
  float p[8]; float z = 0.f;
#pragma unroll
  for (int e = 0; e < 8; ++e) { p[e] = __expf(acc[e] - mx); z += p[e]; }
  int i1 = 0;
#pragma unroll
  for (int e = 1; e < 8; ++e) if (p[e] > p[i1]) i1 = e;
  int i2 = (i1 == 0) ? 1 : 0;
#pragma unroll
  for (int e = 0; e < 8; ++e) if (e != i1 && p[e] > p[i2]) i2 = e;
  if (lane == 0) {
    float inv = 1.f / z;
    ridx[t]  = make_int2(i1, i2);
    rgate[t] = make_float2(p[i1] * inv, p[i2] * inv);
  }
}

// ---------------- capacity positions: rank-major running count -----------------
// one wave (64 threads) per group; assignments processed in order a = r*S + s
__global__ void positions_kernel(const int2* __restrict__ ridx, const float2* __restrict__ rgate,
                                 int* __restrict__ slot_token, float* __restrict__ slot_gate,
                                 int S, int C) {
  int g = blockIdx.x;
  int lane = threadIdx.x;
  unsigned long long ltmask = (1ull << lane) - 1ull;
  int cnt[8];
#pragma unroll
  for (int e = 0; e < 8; ++e) cnt[e] = 0;
  int nch = (2 * S) >> 6;   // S is a multiple of 64 for both streams
  for (int ch = 0; ch < nch; ++ch) {
    int a = (ch << 6) + lane;
    int r = (a >= S) ? 1 : 0;
    int s = a - r * S;
    int2   id = ridx[g * S + s];
    float2 gt = rgate[g * S + s];
    int   e    = r ? id.y : id.x;
    float gate = r ? gt.y : gt.x;
    unsigned long long mymask = 0;
    int add[8];
#pragma unroll
    for (int ee = 0; ee < 8; ++ee) {
      unsigned long long mk = __ballot(e == ee);
      if (e == ee) mymask = mk;
      add[ee] = __popcll(mk);
    }
    int pos = cnt[e] + __popcll(mymask & ltmask);
    if (pos < C) {
      int sl = (e * 8 + g) * C + pos;
      slot_token[sl] = s;
      slot_gate[sl]  = gate;
    }
#pragma unroll
    for (int ee = 0; ee < 8; ++ee) cnt[ee] += add[ee];
  }
}

// ---------------- gather tokens into dense bf16 expert buffers -----------------
// one 64-thread block per (e,g,c) slot row
__global__ void gather_kernel(const float* __restrict__ x, const int* __restrict__ slot_token,
                              bf16* __restrict__ xe, int S, int C) {
  int slot = blockIdx.x;
  int lane = threadIdx.x;
  int g = (slot / C) & 7;
  int s = slot_token[slot];
  bf16* dst = xe + (size_t)slot * D_MODEL;
  const float* xr = x + ((size_t)g * S + (s < 0 ? 0 : s)) * D_MODEL;
#pragma unroll
  for (int j = 0; j < 3; ++j) {
    int idx = j * 256 + lane * 4;
    float4 v;
    if (s >= 0) v = *(const float4*)(xr + idx);
    else        v = make_float4(0.f, 0.f, 0.f, 0.f);
    bf16 o[4] = {(bf16)v.x, (bf16)v.y, (bf16)v.z, (bf16)v.w};
    *(uint2*)(dst + idx) = *(const uint2*)o;
  }
}

// ---------------- fp32 [E][K][N] -> bf16 [E][N][K] (LDS-tiled transpose) -------
__global__ void convt_kernel(const float* __restrict__ src, bf16* __restrict__ dst, int K, int N) {
  __shared__ float tile[32][33];
  int e = blockIdx.z;
  const float* S_ = src + (size_t)e * K * N;
  bf16* D_ = dst + (size_t)e * K * N;
  int n0 = blockIdx.x * 32, k0 = blockIdx.y * 32;
  int tx = threadIdx.x, ty = threadIdx.y;
#pragma unroll
  for (int i = 0; i < 4; ++i)
    tile[ty + 8 * i][tx] = S_[(size_t)(k0 + ty + 8 * i) * N + (n0 + tx)];
  __syncthreads();
#pragma unroll
  for (int i = 0; i < 4; ++i)
    D_[(size_t)(n0 + ty + 8 * i) * K + (k0 + tx)] = (bf16)tile[tx][ty + 8 * i];
}

// ---------------- 128x128 bf16 MFMA GEMM, m97-style single-buffer --------------
// A [E][M][K] bf16 row-major, Bt [E][N][K] bf16 (i.e. B transposed), K%32==0,
// M%128==0, N%128==0. MODE 0: H = gelu(A@B + b1) stored bf16 [E][M][N].
// MODE 1: atomicAdd(Y[token], gate*(A@B + b2)) via slot_token/slot_gate.
template <int MODE>
__launch_bounds__(256, 2)
__global__ void gemm_mfma(const bf16* __restrict__ Aall, const bf16* __restrict__ Btall,
                          const float* __restrict__ biasall, int M, int N, int K,
                          bf16* __restrict__ Hout,
                          const int* __restrict__ slot_token, const float* __restrict__ slot_gate,
                          float* __restrict__ Yout, int C, int S) {
  const int e  = blockIdx.z;
  const int n0 = blockIdx.x * 128;
  const int m0 = blockIdx.y * 128;
  const int tid  = threadIdx.x;
  const int wave = tid >> 6, lane = tid & 63;
  const int wm = (wave >> 1) * 64, wn = (wave & 1) * 64;
  const int lrow = lane & 15, lquad = lane >> 4;

  const bf16* A  = Aall  + (size_t)e * M * K;
  const bf16* Bt = Btall + (size_t)e * N * K;

  __shared__ __align__(16) bf16 As[128 * 32];
  __shared__ __align__(16) bf16 Bs[128 * 32];

  f32x4 acc[4][4];
#pragma unroll
  for (int mi = 0; mi < 4; ++mi)
#pragma unroll
    for (int ni = 0; ni < 4; ++ni) acc[mi][ni] = {0.f, 0.f, 0.f, 0.f};

  // staging: 256 threads x 16B x 2 rounds per 8KB tile; rows have 32 bf16 = 64B
  const int r0 = tid >> 2;          // rows 0..63   (round 0)
  const int r1 = 64 + (tid >> 2);   // rows 64..127 (round 1)
  const int c0 = tid & 3;           // 16B chunk within row
  char* AsB = (char*)As;
  char* BsB = (char*)Bs;
  const int lds0 = wave * 1024;     // wave-uniform LDS base (+ lane*16 by HW)

  const int nsteps = K >> 5;
  for (int kt = 0; kt < nsteps; ++kt) {
    const size_t kb = (size_t)kt * 32 + c0 * 8;  // element offset in K
    lds_load16(A  + (size_t)(m0 + r0) * K + kb, AsB + lds0);
    lds_load16(A  + (size_t)(m0 + r1) * K + kb, AsB + 4096 + lds0);
    lds_load16(Bt + (size_t)(n0 + r0) * K + kb, BsB + lds0);
    lds_load16(Bt + (size_t)(n0 + r1) * K + kb, BsB + 4096 + lds0);
    __syncthreads();
    bf16x8 fa[4], fb[4];
#pragma unroll
    for (int i = 0; i < 4; ++i) {
      fa[i] = *(const bf16x8*)(As + (wm + i * 16 + lrow) * 32 + lquad * 8);
      fb[i] = *(const bf16x8*)(Bs + (wn + i * 16 + lrow) * 32 + lquad * 8);
    }
#pragma unroll
    for (int mi = 0; mi < 4; ++mi)
#pragma unroll
      for (int ni = 0; ni < 4; ++ni)
        acc[mi][ni] = __builtin_amdgcn_mfma_f32_16x16x32_bf16(fa[mi], fb[ni], acc[mi][ni], 0, 0, 0);
    __syncthreads();
  }

  if constexpr (MODE == 0) {
    const float* bias = biasall + (size_t)e * N;
    bf16* H = Hout + (size_t)e * M * N;
#pragma unroll
    for (int ni = 0; ni < 4; ++ni) {
      int gn = n0 + wn + ni * 16 + lrow;
      float b = bias[gn];
#pragma unroll
      for (int mi = 0; mi < 4; ++mi) {
#pragma unroll
        for (int r = 0; r < 4; ++r) {
          int gm = m0 + wm + mi * 16 + lquad * 4 + r;   // C/D: row = quad*4+reg
          float v = acc[mi][ni][r] + b;
          H[(size_t)gm * N + gn] = (bf16)gelu_tanh(v);
        }
      }
    }
  } else {
    const float* bias = biasall + (size_t)e * N;
    const int*   st = slot_token + (size_t)e * M;
    const float* sg = slot_gate  + (size_t)e * M;
#pragma unroll
    for (int mi = 0; mi < 4; ++mi) {
#pragma unroll
      for (int r = 0; r < 4; ++r) {
        int m = m0 + wm + mi * 16 + lquad * 4 + r;
        int s = st[m];
        if (s < 0) continue;                    // empty slot / dropped
        float gate = sg[m];
        int g = m / C;
        float* yrow = Yout + ((size_t)(g * S + s)) * D_MODEL;
#pragma unroll
        for (int ni = 0; ni < 4; ++ni) {
          int gn = n0 + wn + ni * 16 + lrow;
          float v = gate * (acc[mi][ni][r] + bias[gn]);
          atomicAdd(&yrow[gn], v);
        }
      }
    }
  }
}

// ---------------- launch -------------------------------------------------------
extern "C" void kernel_launch(void* const* d_in, const int* in_sizes, int n_in,
                              void* d_out, int out_size, void* d_ws, size_t ws_size,
                              hipStream_t stream) {
  (void)in_sizes; (void)n_in; (void)ws_size;
  const float* x_det  = (const float*)d_in[0];
  const float* x_cls  = (const float*)d_in[1];
  const float* wr_det = (const float*)d_in[2];
  const float* wr_cls = (const float*)d_in[3];
  const float* w1     = (const float*)d_in[4];
  const float* b1     = (const float*)d_in[5];
  const float* w2     = (const float*)d_in[6];
  const float* b2     = (const float*)d_in[7];
  float* out = (float*)d_out;
  char*  ws  = (char*)d_ws;

  bf16*   w1t    = (bf16*)(ws + OFF_W1T);
  bf16*   w2t    = (bf16*)(ws + OFF_W2T);
  bf16*   xe_det = (bf16*)(ws + OFF_XED);
  bf16*   xe_cls = (bf16*)(ws + OFF_XEC);
  bf16*   h_det  = (bf16*)(ws + OFF_HD);
  bf16*   h_cls  = (bf16*)(ws + OFF_HC);
  int2*   ri_det = (int2*)(ws + OFF_RID);
  float2* rg_det = (float2*)(ws + OFF_RGD);
  int2*   ri_cls = (int2*)(ws + OFF_RIC);
  float2* rg_cls = (float2*)(ws + OFF_RGC);
  int*    st_det = (int*)(ws + OFF_STD);
  int*    st_cls = (int*)(ws + OFF_STC);
  float*  sg_det = (float*)(ws + OFF_SGD);
  float*  sg_cls = (float*)(ws + OFF_SGC);

  // zero output (fc2 scatters with atomics); slot tokens -> -1
  hipMemsetAsync(d_out, 0, (size_t)out_size * 4, stream);
  hipMemsetAsync(ws + OFF_STD, 0xFF, SZ_STD + SZ_STC, stream);

  // weights: fp32 [E][K][N] -> bf16 [E][N][K]
  convt_kernel<<<dim3(3072 / 32, 768 / 32, 8), dim3(32, 8), 0, stream>>>(w1, w1t, 768, 3072);
  convt_kernel<<<dim3(768 / 32, 3072 / 32, 8), dim3(32, 8), 0, stream>>>(w2, w2t, 3072, 768);

  // routing
  router_kernel<<<8192 / 4, 256, 0, stream>>>(x_det, wr_det, 8192, ri_det, rg_det);
  router_kernel<<<1024 / 4, 256, 0, stream>>>(x_cls, wr_cls, 1024, ri_cls, rg_cls);
  positions_kernel<<<8, 64, 0, stream>>>(ri_det, rg_det, st_det, sg_det, 1024, 256);
  positions_kernel<<<8, 64, 0, stream>>>(ri_cls, rg_cls, st_cls, sg_cls, 128, 32);

  // gather to dense expert buffers (bf16)
  gather_kernel<<<8 * 8 * 256, 64, 0, stream>>>(x_det, st_det, xe_det, 1024, 256);
  gather_kernel<<<8 * 8 * 32, 64, 0, stream>>>(x_cls, st_cls, xe_cls, 128, 32);

  // fc1: h = gelu(xe @ w1 + b1)
  gemm_mfma<0><<<dim3(3072 / 128, 2048 / 128, 8), 256, 0, stream>>>(
      xe_det, w1t, b1, 2048, 3072, 768, h_det, nullptr, nullptr, nullptr, 0, 0);
  gemm_mfma<0><<<dim3(3072 / 128, 256 / 128, 8), 256, 0, stream>>>(
      xe_cls, w1t, b1, 256, 3072, 768, h_cls, nullptr, nullptr, nullptr, 0, 0);

  // fc2 + gated scatter into output
  gemm_mfma<1><<<dim3(768 / 128, 2048 / 128, 8), 256, 0, stream>>>(
      h_det, w2t, b2, 2048, 768, 3072, nullptr, st_det, sg_det, out, 256, 1024);
  gemm_mfma<1><<<dim3(768 / 128, 256 / 128, 8), 256, 0, stream>>>(
      h_cls, w2t, b2, 256, 768, 3072, nullptr, st_cls, sg_cls, out + (size_t)8 * 1024 * 768, 32, 128);
}

// Round 2
// 606.642 us; speedup vs baseline: 1.1694x; 1.1694x over previous
//
#include <hip/hip_runtime.h>
#include <hip/hip_bf16.h>
#include <math.h>

typedef __bf16 bf16;
typedef __bf16 bf16x8 __attribute__((ext_vector_type(8)));
typedef __bf16 bf16x4 __attribute__((ext_vector_type(4)));
typedef float  f32x4  __attribute__((ext_vector_type(4)));

#define D_MODEL 768
#define MLP_DIM 3072

// ---------------- workspace layout ---------------------------------------------
#define SZ_W1T   ((size_t)8*3072*768*2)        // bf16 [E][N=3072][K=768]
#define SZ_W2T   ((size_t)8*768*3072*2)        // bf16 [E][N=768][K=3072]
#define SZ_XED   ((size_t)8*8*256*768*2)       // bf16 [E][M=2048][768] det
#define SZ_XEC   ((size_t)8*8*32*768*2)        // cls
#define SZ_HD    ((size_t)8*2048*3072*2)       // bf16 [E][M][3072] det
#define SZ_HC    ((size_t)8*256*3072*2)        // cls
#define SZ_YED   ((size_t)8*2048*768*2)        // bf16 fc2 per-slot out det
#define SZ_YEC   ((size_t)8*256*768*2)         // cls
#define SZ_RID   ((size_t)8192*8)
#define SZ_RGD   ((size_t)8192*8)
#define SZ_RIC   ((size_t)1024*8)
#define SZ_RGC   ((size_t)1024*8)
#define SZ_STD   ((size_t)8*8*256*4)           // slot -> token (det)
#define SZ_STC   ((size_t)8*8*32*4)
#define SZ_TSD   ((size_t)2*8192*4)            // token,rank -> global slot (det)
#define SZ_TSC   ((size_t)2*1024*4)

#define OFF_W1T  ((size_t)0)
#define OFF_W2T  (OFF_W1T + SZ_W1T)
#define OFF_XED  (OFF_W2T + SZ_W2T)
#define OFF_XEC  (OFF_XED + SZ_XED)
#define OFF_HD   (OFF_XEC + SZ_XEC)
#define OFF_HC   (OFF_HD  + SZ_HD)
#define OFF_YED  (OFF_HC  + SZ_HC)
#define OFF_YEC  (OFF_YED + SZ_YED)
#define OFF_RID  (OFF_YEC + SZ_YEC)
#define OFF_RGD  (OFF_RID + SZ_RID)
#define OFF_RIC  (OFF_RGD + SZ_RGD)
#define OFF_RGC  (OFF_RIC + SZ_RIC)
#define OFF_STD  (OFF_RGC + SZ_RGC)
#define OFF_STC  (OFF_STD + SZ_STD)            // STD+STC contiguous: one memset(0xFF)
#define OFF_TSD  (OFF_STC + SZ_STC)
#define OFF_TSC  (OFF_TSD + SZ_TSD)

// ---------------- helpers ------------------------------------------------------
__device__ __forceinline__ void lds_load16(const void* g, void* l) {
  __builtin_amdgcn_global_load_lds((__attribute__((address_space(1))) void*)g,
                                   (__attribute__((address_space(3))) void*)l,
                                   16, 0, 0);
}

__device__ __forceinline__ float gelu_tanh(float x) {
  float x3 = x * x * x;
  float t = tanhf(0.7978845608028654f * (x + 0.044715f * x3));
  return 0.5f * x * (1.f + t);
}

// ---------------- router: gates = softmax(x@wr), top-2 -------------------------
__global__ void router_kernel(const float* __restrict__ x, const float* __restrict__ wr,
                              int ntok, int2* __restrict__ ridx, float2* __restrict__ rgate) {
  int wave = threadIdx.x >> 6;
  int lane = threadIdx.x & 63;
  int t = blockIdx.x * 4 + wave;
  if (t >= ntok) return;
  const float* xr = x + (size_t)t * D_MODEL;
  float acc[8];
#pragma unroll
  for (int e = 0; e < 8; ++e) acc[e] = 0.f;
  for (int d = lane; d < D_MODEL; d += 64) {
    float xv = xr[d];
    const float* w = wr + d * 8;
    float4 a = *(const float4*)w;
    float4 b = *(const float4*)(w + 4);
    acc[0] += xv * a.x; acc[1] += xv * a.y; acc[2] += xv * a.z; acc[3] += xv * a.w;
    acc[4] += xv * b.x; acc[5] += xv * b.y; acc[6] += xv * b.z; acc[7] += xv * b.w;
  }
#pragma unroll
  for (int off = 32; off > 0; off >>= 1) {
#pragma unroll
    for (int e = 0; e < 8; ++e) acc[e] += __shfl_xor(acc[e], off, 64);
  }
  float mx = acc[0];
#pragma unroll
  for (int e = 1; e < 8; ++e) mx = fmaxf(mx, acc[e]);
  float p[8]; float z = 0.f;
#pragma unroll
  for (int e = 0; e < 8; ++e) { p[e] = __expf(acc[e] - mx); z += p[e]; }
  int i1 = 0;
#pragma unroll
  for (int e = 1; e < 8; ++e) if (p[e] > p[i1]) i1 = e;
  int i2 = (i1 == 0) ? 1 : 0;
#pragma unroll
  for (int e = 0; e < 8; ++e) if (e != i1 && p[e] > p[i2]) i2 = e;
  if (lane == 0) {
    float inv = 1.f / z;
    ridx[t]  = make_int2(i1, i2);
    rgate[t] = make_float2(p[i1] * inv, p[i2] * inv);
  }
}

// ---------------- capacity positions + inverse (token -> slot) map -------------
__global__ void positions_kernel(const int2* __restrict__ ridx, const float2* __restrict__ rgate,
                                 int* __restrict__ slot_token, int* __restrict__ tok_slot,
                                 int S, int C) {
  int g = blockIdx.x;
  int lane = threadIdx.x;
  int ntok = 8 * S;
  unsigned long long ltmask = (1ull << lane) - 1ull;
  int cnt[8];
#pragma unroll
  for (int e = 0; e < 8; ++e) cnt[e] = 0;
  int nch = (2 * S) >> 6;
  for (int ch = 0; ch < nch; ++ch) {
    int a = (ch << 6) + lane;
    int r = (a >= S) ? 1 : 0;
    int s = a - r * S;
    int2 id = ridx[g * S + s];
    int  e  = r ? id.y : id.x;
    unsigned long long mymask = 0;
    int add[8];
#pragma unroll
    for (int ee = 0; ee < 8; ++ee) {
      unsigned long long mk = __ballot(e == ee);
      if (e == ee) mymask = mk;
      add[ee] = __popcll(mk);
    }
    int pos = cnt[e] + __popcll(mymask & ltmask);
    int sl = (e * 8 + g) * C + pos;       // global slot id == e*M + (g*C+pos)
    if (pos < C) slot_token[sl] = s;
    tok_slot[r * ntok + g * S + s] = (pos < C) ? sl : -1;
#pragma unroll
    for (int ee = 0; ee < 8; ++ee) cnt[ee] += add[ee];
  }
}

// ---------------- gather tokens into dense bf16 expert buffers -----------------
__global__ void gather_kernel(const float* __restrict__ x, const int* __restrict__ slot_token,
                              bf16* __restrict__ xe, int S, int C) {
  int slot = blockIdx.x;
  int lane = threadIdx.x;
  int g = (slot / C) & 7;
  int s = slot_token[slot];
  bf16* dst = xe + (size_t)slot * D_MODEL;
  const float* xr = x + ((size_t)g * S + (s < 0 ? 0 : s)) * D_MODEL;
#pragma unroll
  for (int j = 0; j < 3; ++j) {
    int idx = j * 256 + lane * 4;
    float4 v;
    if (s >= 0) v = *(const float4*)(xr + idx);
    else        v = make_float4(0.f, 0.f, 0.f, 0.f);
    bf16 o[4] = {(bf16)v.x, (bf16)v.y, (bf16)v.z, (bf16)v.w};
    *(uint2*)(dst + idx) = *(const uint2*)o;
  }
}

// ---------------- fp32 [E][K][N] -> bf16 [E][N][K] transpose -------------------
__global__ void convt_kernel(const float* __restrict__ src, bf16* __restrict__ dst, int K, int N) {
  __shared__ float tile[32][33];
  int e = blockIdx.z;
  const float* S_ = src + (size_t)e * K * N;
  bf16* D_ = dst + (size_t)e * K * N;
  int n0 = blockIdx.x * 32, k0 = blockIdx.y * 32;
  int tx = threadIdx.x, ty = threadIdx.y;
#pragma unroll
  for (int i = 0; i < 4; ++i)
    tile[ty + 8 * i][tx] = S_[(size_t)(k0 + ty + 8 * i) * N + (n0 + tx)];
  __syncthreads();
  int tid = ty * 32 + tx;
  int n = tid >> 3, kc = (tid & 7) * 4;
  bf16 o[4] = {(bf16)tile[kc][n], (bf16)tile[kc + 1][n], (bf16)tile[kc + 2][n], (bf16)tile[kc + 3][n]};
  *(uint2*)(D_ + (size_t)(n0 + n) * K + (k0 + kc)) = *(const uint2*)o;
}

// ---------------- combine: out[t] = sum_r gate_r * ye[slot_r] ------------------
__global__ void combine_kernel(const int* __restrict__ tok_slot, const float2* __restrict__ rgate,
                               const bf16* __restrict__ ye, float* __restrict__ out, int ntok) {
  int t = blockIdx.x;
  int lane = threadIdx.x;
  int s1 = tok_slot[t];
  int s2 = tok_slot[ntok + t];
  float2 gg = rgate[t];
  float g1 = (s1 < 0) ? 0.f : gg.x;
  float g2 = (s2 < 0) ? 0.f : gg.y;
  const bf16* y1 = ye + (size_t)(s1 < 0 ? 0 : s1) * D_MODEL;
  const bf16* y2 = ye + (size_t)(s2 < 0 ? 0 : s2) * D_MODEL;
  float* orow = out + (size_t)t * D_MODEL;
#pragma unroll
  for (int j = 0; j < 3; ++j) {
    int idx = j * 256 + lane * 4;
    bf16x4 a = *(const bf16x4*)(y1 + idx);
    bf16x4 b = *(const bf16x4*)(y2 + idx);
    float4 o;
    o.x = g1 * (float)a[0] + g2 * (float)b[0];
    o.y = g1 * (float)a[1] + g2 * (float)b[1];
    o.z = g1 * (float)a[2] + g2 * (float)b[2];
    o.w = g1 * (float)a[3] + g2 * (float)b[3];
    *(float4*)(orow + idx) = o;
  }
}

// ---------------- 128x128 bf16 MFMA GEMM ---------------------------------------
// A [E][M][K] bf16, Bt [E][N][K] bf16. Expert-per-XCD: e = blockIdx.x & 7.
// GELU=1: Out = gelu(A@B + bias) ; GELU=0: Out = A@B + bias   (bf16 [E][M][N])
// LDS K-chunks XOR-swizzled by (row&3) to cut ds_read_b128 bank conflicts.
template <int GELU>
__launch_bounds__(256, 3)
__global__ void gemm_mfma(const bf16* __restrict__ Aall, const bf16* __restrict__ Btall,
                          const float* __restrict__ biasall, int M, int N, int K,
                          int Nm, int Nn, int minner, bf16* __restrict__ Out) {
  const int bid = blockIdx.x;
  const int e   = bid & 7;                 // expert == XCD (blockIdx%8 heuristic)
  const int seq = bid >> 3;
  int m_t, n_t;
  if (minner) { n_t = seq / Nm; m_t = seq - n_t * Nm; }   // fc1: A_e resident in L2
  else        { m_t = seq / Nn; n_t = seq - m_t * Nn; }   // fc2: B_e resident in L2
  const int n0 = n_t * 128;
  const int m0 = m_t * 128;
  const int tid  = threadIdx.x;
  const int wave = tid >> 6, lane = tid & 63;
  const int wm = (wave >> 1) * 64, wn = (wave & 1) * 64;
  const int lrow = lane & 15, lquad = lane >> 4;

  const bf16* A  = Aall  + (size_t)e * M * K;
  const bf16* Bt = Btall + (size_t)e * N * K;

  __shared__ __align__(16) bf16 As[128 * 32];
  __shared__ __align__(16) bf16 Bs[128 * 32];

  f32x4 acc[4][4];
#pragma unroll
  for (int mi = 0; mi < 4; ++mi)
#pragma unroll
    for (int ni = 0; ni < 4; ++ni) acc[mi][ni] = {0.f, 0.f, 0.f, 0.f};

  const int r0 = tid >> 2;            // rows 0..63   (round 0)
  const int r1 = 64 + r0;             // rows 64..127 (round 1), same (row&3)
  const int cA = (((tid & 3) ^ (r0 & 3)) * 8);   // swizzled source K-chunk (elems)
  char* AsB = (char*)As;
  char* BsB = (char*)Bs;
  const int lds0 = wave * 1024;       // wave-uniform LDS base (+ lane*16 by HW)
  const int qS = (lquad ^ (lrow & 3)) * 8;       // swizzled fragment chunk (elems)

  const int nsteps = K >> 5;
  for (int kt = 0; kt < nsteps; ++kt) {
    const size_t kb = (size_t)kt * 32 + cA;
    lds_load16(A  + (size_t)(m0 + r0) * K + kb, AsB + lds0);
    lds_load16(A  + (size_t)(m0 + r1) * K + kb, AsB + 4096 + lds0);
    lds_load16(Bt + (size_t)(n0 + r0) * K + kb, BsB + lds0);
    lds_load16(Bt + (size_t)(n0 + r1) * K + kb, BsB + 4096 + lds0);
    __syncthreads();
    bf16x8 fa[4], fb[4];
#pragma unroll
    for (int i = 0; i < 4; ++i) {
      fa[i] = *(const bf16x8*)(As + (wm + i * 16 + lrow) * 32 + qS);
      fb[i] = *(const bf16x8*)(Bs + (wn + i * 16 + lrow) * 32 + qS);
    }
#pragma unroll
    for (int mi = 0; mi < 4; ++mi)
#pragma unroll
      for (int ni = 0; ni < 4; ++ni)
        acc[mi][ni] = __builtin_amdgcn_mfma_f32_16x16x32_bf16(fa[mi], fb[ni], acc[mi][ni], 0, 0, 0);
    __syncthreads();
  }

  const float* bias = biasall + (size_t)e * N;
  bf16* O = Out + (size_t)e * M * N;
#pragma unroll
  for (int ni = 0; ni < 4; ++ni) {
    int gn = n0 + wn + ni * 16 + lrow;
    float b = bias[gn];
#pragma unroll
    for (int mi = 0; mi < 4; ++mi) {
#pragma unroll
      for (int r = 0; r < 4; ++r) {
        int gm = m0 + wm + mi * 16 + lquad * 4 + r;   // C/D: row = quad*4+reg
        float v = acc[mi][ni][r] + b;
        if (GELU) v = gelu_tanh(v);
        O[(size_t)gm * N + gn] = (bf16)v;
      }
    }
  }
}

// ---------------- launch -------------------------------------------------------
extern "C" void kernel_launch(void* const* d_in, const int* in_sizes, int n_in,
                              void* d_out, int out_size, void* d_ws, size_t ws_size,
                              hipStream_t stream) {
  (void)in_sizes; (void)n_in; (void)ws_size; (void)out_size;
  const float* x_det  = (const float*)d_in[0];
  const float* x_cls  = (const float*)d_in[1];
  const float* wr_det = (const float*)d_in[2];
  const float* wr_cls = (const float*)d_in[3];
  const float* w1     = (const float*)d_in[4];
  const float* b1     = (const float*)d_in[5];
  const float* w2     = (const float*)d_in[6];
  const float* b2     = (const float*)d_in[7];
  float* out = (float*)d_out;
  char*  ws  = (char*)d_ws;

  bf16*   w1t    = (bf16*)(ws + OFF_W1T);
  bf16*   w2t    = (bf16*)(ws + OFF_W2T);
  bf16*   xe_det = (bf16*)(ws + OFF_XED);
  bf16*   xe_cls = (bf16*)(ws + OFF_XEC);
  bf16*   h_det  = (bf16*)(ws + OFF_HD);
  bf16*   h_cls  = (bf16*)(ws + OFF_HC);
  bf16*   ye_det = (bf16*)(ws + OFF_YED);
  bf16*   ye_cls = (bf16*)(ws + OFF_YEC);
  int2*   ri_det = (int2*)(ws + OFF_RID);
  float2* rg_det = (float2*)(ws + OFF_RGD);
  int2*   ri_cls = (int2*)(ws + OFF_RIC);
  float2* rg_cls = (float2*)(ws + OFF_RGC);
  int*    st_det = (int*)(ws + OFF_STD);
  int*    st_cls = (int*)(ws + OFF_STC);
  int*    ts_det = (int*)(ws + OFF_TSD);
  int*    ts_cls = (int*)(ws + OFF_TSC);

  // empty slots -> -1 (STD+STC contiguous)
  hipMemsetAsync(ws + OFF_STD, 0xFF, SZ_STD + SZ_STC, stream);

  // weights: fp32 [E][K][N] -> bf16 [E][N][K]
  convt_kernel<<<dim3(3072 / 32, 768 / 32, 8), dim3(32, 8), 0, stream>>>(w1, w1t, 768, 3072);
  convt_kernel<<<dim3(768 / 32, 3072 / 32, 8), dim3(32, 8), 0, stream>>>(w2, w2t, 3072, 768);

  // routing
  router_kernel<<<8192 / 4, 256, 0, stream>>>(x_det, wr_det, 8192, ri_det, rg_det);
  router_kernel<<<1024 / 4, 256, 0, stream>>>(x_cls, wr_cls, 1024, ri_cls, rg_cls);
  positions_kernel<<<8, 64, 0, stream>>>(ri_det, rg_det, st_det, ts_det, 1024, 256);
  positions_kernel<<<8, 64, 0, stream>>>(ri_cls, rg_cls, st_cls, ts_cls, 128, 32);

  // gather to dense expert buffers (bf16)
  gather_kernel<<<8 * 8 * 256, 64, 0, stream>>>(x_det, st_det, xe_det, 1024, 256);
  gather_kernel<<<8 * 8 * 32, 64, 0, stream>>>(x_cls, st_cls, xe_cls, 128, 32);

  // fc1: h = gelu(xe @ w1 + b1)   (n-outer/m-inner: A_e ~3.1MB resident per XCD)
  gemm_mfma<1><<<8 * 16 * 24, 256, 0, stream>>>(xe_det, w1t, b1, 2048, 3072, 768, 16, 24, 1, h_det);
  gemm_mfma<1><<<8 * 2 * 24,  256, 0, stream>>>(xe_cls, w1t, b1, 256,  3072, 768, 2,  24, 1, h_cls);

  // fc2: ye = h @ w2 + b2         (m-outer/n-inner: B_e ~4.7MB near-resident)
  gemm_mfma<0><<<8 * 16 * 6, 256, 0, stream>>>(h_det, w2t, b2, 2048, 768, 3072, 16, 6, 0, ye_det);
  gemm_mfma<0><<<8 * 2 * 6,  256, 0, stream>>>(h_cls, w2t, b2, 256,  768, 3072, 2,  6, 0, ye_cls);

  // combine: out[t] = sum_r gate_r * ye[slot_r]
  combine_kernel<<<8192, 64, 0, stream>>>(ts_det, rg_det, ye_det, out, 8192);
  combine_kernel<<<1024, 64, 0, stream>>>(ts_cls, rg_cls, ye_cls, out + (size_t)8192 * 768, 1024);
}

// Round 3
// 580.091 us; speedup vs baseline: 1.2229x; 1.0458x over previous
//
#include <hip/hip_runtime.h>
#include <hip/hip_bf16.h>
#include <math.h>

typedef __bf16 bf16;
typedef __bf16 bf16x8 __attribute__((ext_vector_type(8)));
typedef __bf16 bf16x4 __attribute__((ext_vector_type(4)));
typedef float  f32x4  __attribute__((ext_vector_type(4)));

#define D_MODEL 768
#define MLP_DIM 3072

// ---------------- workspace layout ---------------------------------------------
#define SZ_W1T   ((size_t)8*3072*768*2)        // bf16 [E][N=3072][K=768]
#define SZ_W2T   ((size_t)8*768*3072*2)        // bf16 [E][N=768][K=3072]
#define SZ_XED   ((size_t)8*8*256*768*2)       // bf16 [E][M=2048][768] det
#define SZ_XEC   ((size_t)8*8*32*768*2)        // cls
#define SZ_HD    ((size_t)8*2048*3072*2)       // bf16 [E][M][3072] det
#define SZ_HC    ((size_t)8*256*3072*2)        // cls
#define SZ_YED   ((size_t)8*2048*768*2)        // bf16 fc2 per-slot out det
#define SZ_YEC   ((size_t)8*256*768*2)         // cls
#define SZ_RID   ((size_t)8192*8)
#define SZ_RGD   ((size_t)8192*8)
#define SZ_RIC   ((size_t)1024*8)
#define SZ_RGC   ((size_t)1024*8)
#define SZ_STD   ((size_t)8*8*256*4)           // slot -> token (det)
#define SZ_STC   ((size_t)8*8*32*4)
#define SZ_TSD   ((size_t)2*8192*4)            // token,rank -> global slot (det)
#define SZ_TSC   ((size_t)2*1024*4)

#define OFF_W1T  ((size_t)0)
#define OFF_W2T  (OFF_W1T + SZ_W1T)
#define OFF_XED  (OFF_W2T + SZ_W2T)
#define OFF_XEC  (OFF_XED + SZ_XED)
#define OFF_HD   (OFF_XEC + SZ_XEC)
#define OFF_HC   (OFF_HD  + SZ_HD)
#define OFF_YED  (OFF_HC  + SZ_HC)
#define OFF_YEC  (OFF_YED + SZ_YED)
#define OFF_RID  (OFF_YEC + SZ_YEC)
#define OFF_RGD  (OFF_RID + SZ_RID)
#define OFF_RIC  (OFF_RGD + SZ_RGD)
#define OFF_RGC  (OFF_RIC + SZ_RIC)
#define OFF_STD  (OFF_RGC + SZ_RGC)
#define OFF_STC  (OFF_STD + SZ_STD)            // STD+STC contiguous: one memset(0xFF)
#define OFF_TSD  (OFF_STC + SZ_STC)
#define OFF_TSC  (OFF_TSD + SZ_TSD)

// ---------------- helpers ------------------------------------------------------
__device__ __forceinline__ void lds_load16(const void* g, void* l) {
  __builtin_amdgcn_global_load_lds((__attribute__((address_space(1))) void*)g,
                                   (__attribute__((address_space(3))) void*)l,
                                   16, 0, 0);
}

// tanh-gelu via exp: tanh(y) = 1 - 2/(e^{2y}+1). Saturates correctly at +/-inf.
__device__ __forceinline__ float gelu_fast(float x) {
  float y = 0.7978845608028654f * x * (1.f + 0.044715f * x * x);
  float e = __expf(2.f * y);
  float t = 1.f - 2.f / (e + 1.f);
  return 0.5f * x * (1.f + t);
}

// ---------------- router: gates = softmax(x@wr), top-2 -------------------------
__global__ void router_kernel(const float* __restrict__ x, const float* __restrict__ wr,
                              int ntok, int2* __restrict__ ridx, float2* __restrict__ rgate) {
  int wave = threadIdx.x >> 6;
  int lane = threadIdx.x & 63;
  int t = blockIdx.x * 4 + wave;
  if (t >= ntok) return;
  const float* xr = x + (size_t)t * D_MODEL;
  float acc[8];
#pragma unroll
  for (int e = 0; e < 8; ++e) acc[e] = 0.f;
  for (int d = lane; d < D_MODEL; d += 64) {
    float xv = xr[d];
    const float* w = wr + d * 8;
    float4 a = *(const float4*)w;
    float4 b = *(const float4*)(w + 4);
    acc[0] += xv * a.x; acc[1] += xv * a.y; acc[2] += xv * a.z; acc[3] += xv * a.w;
    acc[4] += xv * b.x; acc[5] += xv * b.y; acc[6] += xv * b.z; acc[7] += xv * b.w;
  }
#pragma unroll
  for (int off = 32; off > 0; off >>= 1) {
#pragma unroll
    for (int e = 0; e < 8; ++e) acc[e] += __shfl_xor(acc[e], off, 64);
  }
  float mx = acc[0];
#pragma unroll
  for (int e = 1; e < 8; ++e) mx = fmaxf(mx, acc[e]);
  float p[8]; float z = 0.f;
#pragma unroll
  for (int e = 0; e < 8; ++e) { p[e] = __expf(acc[e] - mx); z += p[e]; }
  int i1 = 0;
#pragma unroll
  for (int e = 1; e < 8; ++e) if (p[e] > p[i1]) i1 = e;
  int i2 = (i1 == 0) ? 1 : 0;
#pragma unroll
  for (int e = 0; e < 8; ++e) if (e != i1 && p[e] > p[i2]) i2 = e;
  if (lane == 0) {
    float inv = 1.f / z;
    ridx[t]  = make_int2(i1, i2);
    rgate[t] = make_float2(p[i1] * inv, p[i2] * inv);
  }
}

// ---------------- capacity positions + inverse (token -> slot) map -------------
__global__ void positions_kernel(const int2* __restrict__ ridx, const float2* __restrict__ rgate,
                                 int* __restrict__ slot_token, int* __restrict__ tok_slot,
                                 int S, int C) {
  int g = blockIdx.x;
  int lane = threadIdx.x;
  int ntok = 8 * S;
  unsigned long long ltmask = (1ull << lane) - 1ull;
  int cnt[8];
#pragma unroll
  for (int e = 0; e < 8; ++e) cnt[e] = 0;
  int nch = (2 * S) >> 6;
  for (int ch = 0; ch < nch; ++ch) {
    int a = (ch << 6) + lane;
    int r = (a >= S) ? 1 : 0;
    int s = a - r * S;
    int2 id = ridx[g * S + s];
    int  e  = r ? id.y : id.x;
    unsigned long long mymask = 0;
    int add[8];
#pragma unroll
    for (int ee = 0; ee < 8; ++ee) {
      unsigned long long mk = __ballot(e == ee);
      if (e == ee) mymask = mk;
      add[ee] = __popcll(mk);
    }
    int pos = cnt[e] + __popcll(mymask & ltmask);
    int sl = (e * 8 + g) * C + pos;       // global slot id == e*M + (g*C+pos)
    if (pos < C) slot_token[sl] = s;
    tok_slot[r * ntok + g * S + s] = (pos < C) ? sl : -1;
#pragma unroll
    for (int ee = 0; ee < 8; ++ee) cnt[ee] += add[ee];
  }
}

// ---------------- gather tokens into dense bf16 expert buffers -----------------
// 256 threads: 4 slots per block
__global__ void gather_kernel(const float* __restrict__ x, const int* __restrict__ slot_token,
                              bf16* __restrict__ xe, int S, int C) {
  int slot = blockIdx.x * 4 + (threadIdx.x >> 6);
  int lane = threadIdx.x & 63;
  int g = (slot / C) & 7;
  int s = slot_token[slot];
  bf16* dst = xe + (size_t)slot * D_MODEL;
  const float* xr = x + ((size_t)g * S + (s < 0 ? 0 : s)) * D_MODEL;
#pragma unroll
  for (int j = 0; j < 3; ++j) {
    int idx = j * 256 + lane * 4;
    float4 v;
    if (s >= 0) v = *(const float4*)(xr + idx);
    else        v = make_float4(0.f, 0.f, 0.f, 0.f);
    bf16 o[4] = {(bf16)v.x, (bf16)v.y, (bf16)v.z, (bf16)v.w};
    *(uint2*)(dst + idx) = *(const uint2*)o;
  }
}

// ---------------- fp32 [E][K][N] -> bf16 [E][N][K] transpose -------------------
__global__ void convt_kernel(const float* __restrict__ src, bf16* __restrict__ dst, int K, int N) {
  __shared__ float tile[32][33];
  int e = blockIdx.z;
  const float* S_ = src + (size_t)e * K * N;
  bf16* D_ = dst + (size_t)e * K * N;
  int n0 = blockIdx.x * 32, k0 = blockIdx.y * 32;
  int tx = threadIdx.x, ty = threadIdx.y;
#pragma unroll
  for (int i = 0; i < 4; ++i)
    tile[ty + 8 * i][tx] = S_[(size_t)(k0 + ty + 8 * i) * N + (n0 + tx)];
  __syncthreads();
  int tid = ty * 32 + tx;
  int n = tid >> 3, kc = (tid & 7) * 4;
  bf16 o[4] = {(bf16)tile[kc][n], (bf16)tile[kc + 1][n], (bf16)tile[kc + 2][n], (bf16)tile[kc + 3][n]};
  *(uint2*)(D_ + (size_t)(n0 + n) * K + (k0 + kc)) = *(const uint2*)o;
}

// ---------------- combine: out[t] = sum_r gate_r * ye[slot_r] ------------------
// 256 threads: 4 tokens per block
__global__ void combine_kernel(const int* __restrict__ tok_slot, const float2* __restrict__ rgate,
                               const bf16* __restrict__ ye, float* __restrict__ out, int ntok) {
  int t = blockIdx.x * 4 + (threadIdx.x >> 6);
  int lane = threadIdx.x & 63;
  int s1 = tok_slot[t];
  int s2 = tok_slot[ntok + t];
  float2 gg = rgate[t];
  float g1 = (s1 < 0) ? 0.f : gg.x;
  float g2 = (s2 < 0) ? 0.f : gg.y;
  const bf16* y1 = ye + (size_t)(s1 < 0 ? 0 : s1) * D_MODEL;
  const bf16* y2 = ye + (size_t)(s2 < 0 ? 0 : s2) * D_MODEL;
  float* orow = out + (size_t)t * D_MODEL;
#pragma unroll
  for (int j = 0; j < 3; ++j) {
    int idx = j * 256 + lane * 4;
    bf16x4 a = *(const bf16x4*)(y1 + idx);
    bf16x4 b = *(const bf16x4*)(y2 + idx);
    float4 o;
    o.x = g1 * (float)a[0] + g2 * (float)b[0];
    o.y = g1 * (float)a[1] + g2 * (float)b[1];
    o.z = g1 * (float)a[2] + g2 * (float)b[2];
    o.w = g1 * (float)a[3] + g2 * (float)b[3];
    *(float4*)(orow + idx) = o;
  }
}

// ---------------- 128x128 bf16 MFMA GEMM ---------------------------------------
// A [E][M][K] bf16, Bt [E][N][K] bf16. Expert-per-XCD: e = blockIdx.x & 7.
// GELU=1: Out = gelu(A@B + bias) ; GELU=0: Out = A@B + bias   (bf16 [E][M][N])
// Epilogue stages C through LDS (16B-chunk XOR swizzle) -> coalesced b128 stores.
template <int GELU>
__launch_bounds__(256, 3)
__global__ void gemm_mfma(const bf16* __restrict__ Aall, const bf16* __restrict__ Btall,
                          const float* __restrict__ biasall, int M, int N, int K,
                          int Nm, int Nn, int minner, bf16* __restrict__ Out) {
  const int bid = blockIdx.x;
  const int e   = bid & 7;                 // expert == XCD (blockIdx%8 heuristic)
  const int seq = bid >> 3;
  int m_t, n_t;
  if (minner) { n_t = seq / Nm; m_t = seq - n_t * Nm; }   // fc1: A_e resident in L2
  else        { m_t = seq / Nn; n_t = seq - m_t * Nn; }   // fc2: B_e resident in L2
  const int n0 = n_t * 128;
  const int m0 = m_t * 128;
  const int tid  = threadIdx.x;
  const int wave = tid >> 6, lane = tid & 63;
  const int wm = (wave >> 1) * 64, wn = (wave & 1) * 64;
  const int lrow = lane & 15, lquad = lane >> 4;

  const bf16* A  = Aall  + (size_t)e * M * K;
  const bf16* Bt = Btall + (size_t)e * N * K;

  // 32 KB: K-loop uses first 16 KB (As|Bs); epilogue reuses all 32 KB as C-tile
  __shared__ __align__(16) bf16 smem[128 * 128];
  bf16* As = smem;
  bf16* Bs = smem + 128 * 32;

  // bias fragment (4 cols per lane), loaded early
  const float* bias = biasall + (size_t)e * N;
  float bfr[4];
#pragma unroll
  for (int ni = 0; ni < 4; ++ni) bfr[ni] = bias[n0 + wn + ni * 16 + lrow];

  f32x4 acc[4][4];
#pragma unroll
  for (int mi = 0; mi < 4; ++mi)
#pragma unroll
    for (int ni = 0; ni < 4; ++ni) acc[mi][ni] = {0.f, 0.f, 0.f, 0.f};

  const int r0 = tid >> 2;            // rows 0..63   (round 0)
  const int r1 = 64 + r0;             // rows 64..127 (round 1), same (row&3)
  const int cA = (((tid & 3) ^ (r0 & 3)) * 8);   // swizzled source K-chunk (elems)
  char* AsB = (char*)As;
  char* BsB = (char*)Bs;
  const int lds0 = wave * 1024;       // wave-uniform LDS base (+ lane*16 by HW)
  const int qS = (lquad ^ (lrow & 3)) * 8;       // swizzled fragment chunk (elems)

  const int nsteps = K >> 5;
  for (int kt = 0; kt < nsteps; ++kt) {
    const size_t kb = (size_t)kt * 32 + cA;
    lds_load16(A  + (size_t)(m0 + r0) * K + kb, AsB + lds0);
    lds_load16(A  + (size_t)(m0 + r1) * K + kb, AsB + 4096 + lds0);
    lds_load16(Bt + (size_t)(n0 + r0) * K + kb, BsB + lds0);
    lds_load16(Bt + (size_t)(n0 + r1) * K + kb, BsB + 4096 + lds0);
    __syncthreads();
    bf16x8 fa[4], fb[4];
#pragma unroll
    for (int i = 0; i < 4; ++i) {
      fa[i] = *(const bf16x8*)(As + (wm + i * 16 + lrow) * 32 + qS);
      fb[i] = *(const bf16x8*)(Bs + (wn + i * 16 + lrow) * 32 + qS);
    }
#pragma unroll
    for (int mi = 0; mi < 4; ++mi)
#pragma unroll
      for (int ni = 0; ni < 4; ++ni)
        acc[mi][ni] = __builtin_amdgcn_mfma_f32_16x16x32_bf16(fa[mi], fb[ni], acc[mi][ni], 0, 0, 0);
    __syncthreads();
  }

  // ---- epilogue: acc -> LDS (swizzled) -> coalesced b128 global stores --------
  // C/D layout: col = lane&15 (+16*ni), row = lquad*4 + r (+16*mi)
#pragma unroll
  for (int mi = 0; mi < 4; ++mi) {
#pragma unroll
    for (int r = 0; r < 4; ++r) {
      int row = wm + mi * 16 + lquad * 4 + r;
#pragma unroll
      for (int ni = 0; ni < 4; ++ni) {
        int colL = wn + ni * 16 + lrow;
        float v = acc[mi][ni][r] + bfr[ni];
        if (GELU) v = gelu_fast(v);
        int chunk = (colL >> 3) ^ (row & 7);           // 16B-chunk swizzle
        smem[row * 128 + chunk * 8 + (colL & 7)] = (bf16)v;
      }
    }
  }
  __syncthreads();
  bf16* O = Out + (size_t)e * M * N;
#pragma unroll
  for (int it = 0; it < 8; ++it) {
    int idx = it * 256 + tid;          // 0..2047
    int row = idx >> 4;                // 0..127
    int ck  = idx & 15;
    int pchunk = ck ^ (row & 7);
    bf16x8 vv = *(const bf16x8*)(smem + row * 128 + pchunk * 8);
    *(bf16x8*)(O + (size_t)(m0 + row) * N + n0 + ck * 8) = vv;
  }
}

// ---------------- launch -------------------------------------------------------
extern "C" void kernel_launch(void* const* d_in, const int* in_sizes, int n_in,
                              void* d_out, int out_size, void* d_ws, size_t ws_size,
                              hipStream_t stream) {
  (void)in_sizes; (void)n_in; (void)ws_size; (void)out_size;
  const float* x_det  = (const float*)d_in[0];
  const float* x_cls  = (const float*)d_in[1];
  const float* wr_det = (const float*)d_in[2];
  const float* wr_cls = (const float*)d_in[3];
  const float* w1     = (const float*)d_in[4];
  const float* b1     = (const float*)d_in[5];
  const float* w2     = (const float*)d_in[6];
  const float* b2     = (const float*)d_in[7];
  float* out = (float*)d_out;
  char*  ws  = (char*)d_ws;

  bf16*   w1t    = (bf16*)(ws + OFF_W1T);
  bf16*   w2t    = (bf16*)(ws + OFF_W2T);
  bf16*   xe_det = (bf16*)(ws + OFF_XED);
  bf16*   xe_cls = (bf16*)(ws + OFF_XEC);
  bf16*   h_det  = (bf16*)(ws + OFF_HD);
  bf16*   h_cls  = (bf16*)(ws + OFF_HC);
  bf16*   ye_det = (bf16*)(ws + OFF_YED);
  bf16*   ye_cls = (bf16*)(ws + OFF_YEC);
  int2*   ri_det = (int2*)(ws + OFF_RID);
  float2* rg_det = (float2*)(ws + OFF_RGD);
  int2*   ri_cls = (int2*)(ws + OFF_RIC);
  float2* rg_cls = (float2*)(ws + OFF_RGC);
  int*    st_det = (int*)(ws + OFF_STD);
  int*    st_cls = (int*)(ws + OFF_STC);
  int*    ts_det = (int*)(ws + OFF_TSD);
  int*    ts_cls = (int*)(ws + OFF_TSC);

  // empty slots -> -1 (STD+STC contiguous)
  hipMemsetAsync(ws + OFF_STD, 0xFF, SZ_STD + SZ_STC, stream);

  // weights: fp32 [E][K][N] -> bf16 [E][N][K]
  convt_kernel<<<dim3(3072 / 32, 768 / 32, 8), dim3(32, 8), 0, stream>>>(w1, w1t, 768, 3072);
  convt_kernel<<<dim3(768 / 32, 3072 / 32, 8), dim3(32, 8), 0, stream>>>(w2, w2t, 3072, 768);

  // routing
  router_kernel<<<8192 / 4, 256, 0, stream>>>(x_det, wr_det, 8192, ri_det, rg_det);
  router_kernel<<<1024 / 4, 256, 0, stream>>>(x_cls, wr_cls, 1024, ri_cls, rg_cls);
  positions_kernel<<<8, 64, 0, stream>>>(ri_det, rg_det, st_det, ts_det, 1024, 256);
  positions_kernel<<<8, 64, 0, stream>>>(ri_cls, rg_cls, st_cls, ts_cls, 128, 32);

  // gather to dense expert buffers (bf16)
  gather_kernel<<<8 * 8 * 256 / 4, 256, 0, stream>>>(x_det, st_det, xe_det, 1024, 256);
  gather_kernel<<<8 * 8 * 32 / 4, 256, 0, stream>>>(x_cls, st_cls, xe_cls, 128, 32);

  // fc1: h = gelu(xe @ w1 + b1)   (n-outer/m-inner: A_e ~3.1MB resident per XCD)
  gemm_mfma<1><<<8 * 16 * 24, 256, 0, stream>>>(xe_det, w1t, b1, 2048, 3072, 768, 16, 24, 1, h_det);
  gemm_mfma<1><<<8 * 2 * 24,  256, 0, stream>>>(xe_cls, w1t, b1, 256,  3072, 768, 2,  24, 1, h_cls);

  // fc2: ye = h @ w2 + b2         (m-outer/n-inner: B_e ~4.7MB near-resident)
  gemm_mfma<0><<<8 * 16 * 6, 256, 0, stream>>>(h_det, w2t, b2, 2048, 768, 3072, 16, 6, 0, ye_det);
  gemm_mfma<0><<<8 * 2 * 6,  256, 0, stream>>>(h_cls, w2t, b2, 256,  768, 3072, 2,  6, 0, ye_cls);

  // combine: out[t] = sum_r gate_r * ye[slot_r]
  combine_kernel<<<8192 / 4, 256, 0, stream>>>(ts_det, rg_det, ye_det, out, 8192);
  combine_kernel<<<1024 / 4, 256, 0, stream>>>(ts_cls, rg_cls, ye_cls, out + (size_t)8192 * 768, 1024);
}